// Round 4
// baseline (1543.837 us; speedup 1.0000x reference)
//
#include <hip/hip_runtime.h>
#include <hip/hip_fp16.h>
#include <math.h>

// B=32, N=1024 Sinkhorn (20 iters). scores@W+b cancels under the first row-lse
// -> inputs 0..2 dead. Linear domain: K = exp(g - 8) (fp16, scale-invariant),
// u_i = 1/(K v)_i, v_j = 1/(K^T u)_j, out = K .* (u v^T).
//
// K lives ENTIRELY IN REGISTERS for the whole solve.
// ROUND-2 LESSON: 1024-thread blocks = 4 waves/SIMD = 128-VGPR cap -> spill.
// ROUND-3 LESSON: __launch_bounds__(512,2) sets only MIN waves/EU; compiler's
// occupancy heuristic still targeted 4 waves/EU, capped at 128 VGPRs, and
// spilled kr to scratch (VGPR_Count=128, FETCH 1.6GB, 1212us). Fix: pin the
// window with amdgpu_waves_per_eu(2,2) (min AND max) -> 256-VGPR budget.
//   grid = 256 blocks (8 per batch) x 512 threads, 1 block/CU.
//   wave (8/block) owns 16 rows; lane owns col pairs j = c*128 + 2*lane;
//   kr[16][8] __half2 = 128 VGPRs/thread = 256 KiB/CU = 64 MiB chip-wide.
// Row pass: wave-local shuffle reduce. Col pass: LDS reduce over 8 waves ->
// one atomicAdd per col per block -> 8-block arrival counter per (batch,iter)
// -> coherent readback. Plain launch (graph-capture safe); 1 block/CU at
// grid==CU-count makes deadlock unreachable; spin bounded as insurance.
// Global traffic: read g once (134 MB) + write out once (134 MB) + ~3 MB/iter.
#define BB 32
#define NN 1024
#define SHIFT 8.0f
#define GS_ITERS 20

__global__ __attribute__((amdgpu_flat_work_group_size(512, 512),
                          amdgpu_waves_per_eu(2, 2)))
void sinkhorn_persist(
    const float* __restrict__ g, float* __restrict__ out,
    float* __restrict__ colsum, int* __restrict__ cnt)
{
    const int b    = blockIdx.x >> 3;     // batch
    const int blk  = blockIdx.x & 7;      // row-chunk within batch (128 rows)
    const int wave = threadIdx.x >> 6;    // 0..7
    const int lane = threadIdx.x & 63;
    const int tid  = threadIdx.x;         // 0..511
    const int row0 = blk * 128 + wave * 16;

    const float* gb = g + ((size_t)b << 20);
    float* ob = out + ((size_t)b << 20);

    __shared__ float sm[8][1024];         // 32 KiB

    __half2 kr[16][8];                    // K fragment: 16 rows x 8 col-pairs
    float u[16];
    float vr[16];

    // ---- load g (float2), exp(g-SHIFT), pack fp16; fp32 row sums -> u ----
    #pragma unroll
    for (int p = 0; p < 16; ++p) {
        const float2* grow = (const float2*)(gb + (((size_t)(row0 + p)) << 10)) + lane;
        float s = 0.f;
        #pragma unroll
        for (int c = 0; c < 8; ++c) {
            float2 gg = grow[c * 64];                 // cols c*128 + 2*lane, +1
            float e0 = __expf(gg.x - SHIFT);
            float e1 = __expf(gg.y - SHIFT);
            s += e0 + e1;
            kr[p][c] = __floats2half2_rn(e0, e1);
        }
        #pragma unroll
        for (int off = 32; off; off >>= 1) s += __shfl_xor(s, off);
        u[p] = 1.0f / s;
    }

    #pragma unroll 1
    for (int it = 0; it < GS_ITERS; ++it) {
        // ---- col partials over this wave's 16 rows (register-local) ----
        float cs[16];
        #pragma unroll
        for (int c = 0; c < 16; ++c) cs[c] = 0.f;
        #pragma unroll
        for (int p = 0; p < 16; ++p) {
            const float up = u[p];
            #pragma unroll
            for (int c = 0; c < 8; ++c) {
                float2 f = __half22float2(kr[p][c]);
                cs[2*c]   = fmaf(f.x, up, cs[2*c]);
                cs[2*c+1] = fmaf(f.y, up, cs[2*c+1]);
            }
        }
        // LDS reduce across 8 waves (float2 stores, 2-way alias = free)
        #pragma unroll
        for (int c = 0; c < 8; ++c)
            ((float2*)&sm[wave][0])[c * 64 + lane] = make_float2(cs[2*c], cs[2*c+1]);
        __syncthreads();

        // each thread reduces 2 columns: tid and tid+512
        float bp0 = 0.f, bp1 = 0.f;
        #pragma unroll
        for (int w = 0; w < 8; ++w) {
            bp0 += sm[w][tid];
            bp1 += sm[w][tid + 512];
        }
        float* csit = colsum + (((size_t)(b * GS_ITERS + it)) << 10);
        atomicAdd(csit + tid, bp0);       // device-scope atomics (coherent)
        atomicAdd(csit + tid + 512, bp1);
        __syncthreads();                  // barrier drains vmcnt: adds issued

        // ---- 8-block arrival sync for this (batch, iter) ----
        if (tid == 0) {
            int* c8 = cnt + b * GS_ITERS + it;
            __hip_atomic_fetch_add(c8, 1, __ATOMIC_ACQ_REL, __HIP_MEMORY_SCOPE_AGENT);
            int spins = 0;
            while (__hip_atomic_load(c8, __ATOMIC_ACQUIRE, __HIP_MEMORY_SCOPE_AGENT) < 8) {
                __builtin_amdgcn_s_sleep(8);
                if (++spins > (1 << 22)) break;   // ~1s insurance: never hang
            }
        }
        __syncthreads();

        // coherent readback (agent-scope bypasses stale L1), bcast via LDS
        float tot0 = __hip_atomic_load(csit + tid,       __ATOMIC_RELAXED, __HIP_MEMORY_SCOPE_AGENT);
        float tot1 = __hip_atomic_load(csit + tid + 512, __ATOMIC_RELAXED, __HIP_MEMORY_SCOPE_AGENT);
        sm[0][tid]       = 1.0f / tot0;
        sm[0][tid + 512] = 1.0f / tot1;
        __syncthreads();
        #pragma unroll
        for (int c = 0; c < 8; ++c) {
            float2 vv = ((const float2*)&sm[0][0])[c * 64 + lane];
            vr[2*c] = vv.x; vr[2*c+1] = vv.y;
        }

        // ---- row pass -> new u (skip after last col pass) ----
        if (it < GS_ITERS - 1) {
            #pragma unroll
            for (int p = 0; p < 16; ++p) {
                float s = 0.f;
                #pragma unroll
                for (int c = 0; c < 8; ++c) {
                    float2 f = __half22float2(kr[p][c]);
                    s = fmaf(f.x, vr[2*c],   s);
                    s = fmaf(f.y, vr[2*c+1], s);
                }
                #pragma unroll
                for (int off = 32; off; off >>= 1) s += __shfl_xor(s, off);
                u[p] = 1.0f / s;
            }
        }
        __syncthreads();                  // protect sm before next iter writes
    }

    // ---- out = K .* (u v^T), coalesced float2 stores ----
    #pragma unroll
    for (int p = 0; p < 16; ++p) {
        float2* orow = (float2*)(ob + (((size_t)(row0 + p)) << 10)) + lane;
        const float up = u[p];
        #pragma unroll
        for (int c = 0; c < 8; ++c) {
            float2 f = __half22float2(kr[p][c]);
            orow[c * 64] = make_float2(f.x * up * vr[2*c], f.y * up * vr[2*c+1]);
        }
    }
}

// ---------- fallback path (tiny ws, log-domain, kernel-per-step) ----------

template<bool USE_V>
__global__ __launch_bounds__(256) void row_step(const float* __restrict__ g,
                                                const float* __restrict__ v,
                                                float* __restrict__ t) {
    const int wave = threadIdx.x >> 6, lane = threadIdx.x & 63;
    const int row = blockIdx.x * 4 + wave;
    const int b = row >> 10;
    const float4* grow = (const float4*)(g + ((size_t)row << 10));
    const float4* vrow = (const float4*)(v + ((size_t)b << 10));
    float x[16];
    #pragma unroll
    for (int k = 0; k < 4; k++) {
        float4 gg = grow[lane + 64 * k];
        if (USE_V) {
            float4 vv = vrow[lane + 64 * k];
            x[4*k+0] = gg.x + vv.x; x[4*k+1] = gg.y + vv.y;
            x[4*k+2] = gg.z + vv.z; x[4*k+3] = gg.w + vv.w;
        } else {
            x[4*k+0] = gg.x; x[4*k+1] = gg.y; x[4*k+2] = gg.z; x[4*k+3] = gg.w;
        }
    }
    float m = -INFINITY;
    #pragma unroll
    for (int k = 0; k < 16; k++) m = fmaxf(m, x[k]);
    #pragma unroll
    for (int off = 32; off; off >>= 1) m = fmaxf(m, __shfl_xor(m, off));
    float s = 0.f;
    #pragma unroll
    for (int k = 0; k < 16; k++) s += __expf(x[k] - m);
    #pragma unroll
    for (int off = 32; off; off >>= 1) s += __shfl_xor(s, off);
    if (lane == 0) t[row] = -(m + __logf(s));
}

__global__ __launch_bounds__(256) void col_step(const float* __restrict__ g,
                                                const float* __restrict__ t,
                                                float* __restrict__ v) {
    const int b = blockIdx.x >> 4, tile = blockIdx.x & 15;
    const int tx = threadIdx.x & 63, ty = threadIdx.x >> 6;
    const int j = tile * 64 + tx;
    const float* gp = g + ((size_t)b << 20) + j;
    const float* tp = t + (b << 10);
    float m = -INFINITY, s = 0.f;
    for (int it = 0; it < 256; it += 8) {
        float xv[8];
        #pragma unroll
        for (int u2 = 0; u2 < 8; u2++) {
            int i = ((it + u2) << 2) + ty;
            xv[u2] = gp[(size_t)i << 10] + tp[i];
        }
        #pragma unroll
        for (int u2 = 0; u2 < 8; u2++) {
            float nm = fmaxf(m, xv[u2]);
            s = s * __expf(m - nm) + __expf(xv[u2] - nm);
            m = nm;
        }
    }
    __shared__ float sm[4][64];
    __shared__ float ss[4][64];
    sm[ty][tx] = m; ss[ty][tx] = s;
    __syncthreads();
    if (ty == 0) {
        float M = sm[0][tx], S = ss[0][tx];
        #pragma unroll
        for (int k = 1; k < 4; k++) {
            float mk = sm[k][tx], sk = ss[k][tx];
            float nm = fmaxf(M, mk);
            S = S * __expf(M - nm) + sk * __expf(mk - nm);
            M = nm;
        }
        v[(b << 10) + j] = -(M + __logf(S));
    }
}

__global__ __launch_bounds__(256) void finalize_k(const float* __restrict__ g,
                                                  const float* __restrict__ t,
                                                  const float* __restrict__ v,
                                                  float* __restrict__ out) {
    const size_t idx4 = (size_t)blockIdx.x * 256 + threadIdx.x;
    const size_t base = idx4 << 2;
    const int row = (int)(base >> 10), b = row >> 10;
    const int j = (int)(base & 1023);
    const float ti = t[row];
    float4 gg = ((const float4*)g)[idx4];
    float4 vv = ((const float4*)(v + ((size_t)b << 10)))[j >> 2];
    float4 o;
    o.x = __expf(gg.x + ti + vv.x);
    o.y = __expf(gg.y + ti + vv.y);
    o.z = __expf(gg.z + ti + vv.z);
    o.w = __expf(gg.w + ti + vv.w);
    ((float4*)out)[idx4] = o;
}

extern "C" void kernel_launch(void* const* d_in, const int* in_sizes, int n_in,
                              void* d_out, int out_size, void* d_ws, size_t ws_size,
                              hipStream_t stream) {
    const float* g = (const float*)d_in[3];   // gumbel noise; inputs 0..2 dead
    float* out = (float*)d_out;
    const size_t needCS  = (size_t)BB * GS_ITERS * NN * sizeof(float);  // 2.62 MB
    const size_t needCnt = (size_t)BB * GS_ITERS * sizeof(int);         // 2.5 KB

    if (ws_size >= needCS + needCnt) {
        float* colsum = (float*)d_ws;
        int* cnt = (int*)((char*)d_ws + needCS);
        hipMemsetAsync(d_ws, 0, needCS + needCnt, stream);
        sinkhorn_persist<<<BB * 8, 512, 0, stream>>>(g, out, colsum, cnt);
    } else {
        float* t = (float*)d_ws;
        float* v = t + BB * NN;
        row_step<false><<<8192, 256, 0, stream>>>(g, nullptr, t);
        col_step<<<512, 256, 0, stream>>>(g, t, v);
        for (int it = 1; it < 20; it++) {
            row_step<true><<<8192, 256, 0, stream>>>(g, v, t);
            col_step<<<512, 256, 0, stream>>>(g, t, v);
        }
        finalize_k<<<32768, 256, 0, stream>>>(g, t, v, out);
    }
}

// Round 5
// 790.720 us; speedup vs baseline: 1.9524x; 1.9524x over previous
//
#include <hip/hip_runtime.h>
#include <hip/hip_fp16.h>
#include <math.h>

// B=32, N=1024 Sinkhorn (20 iters). scores@W+b cancels under the first row-lse
// -> inputs 0..2 dead. Linear domain: K = exp(g - 8) (fp16, scale-invariant),
// u_i = 1/(K v)_i, v_j = 1/(K^T u)_j, out = K .* (u v^T).
//
// ROUND-2..4 LESSONS: the backend pins this kernel to a 128-VGPR budget no
// matter what launch-bounds/waves-per-eu hints we give (VGPR_Count=128, kr
// spilled to scratch, FETCH 1.6GB, ~1.3ms). So: STOP needing 256 VGPRs.
// K is split REGISTERS + LDS so demand <= 128 VGPRs by construction:
//   grid = 256 blocks (8 per batch) x 512 threads (8 waves), 1 block/CU
//   (LDS-capped: 147456 B of 160 KiB). Per block: 128 rows.
//     - rows [0,64):  registers, kr[8][8] __half2 = 64 VGPRs (8 rows/wave)
//     - rows [64,128): LDS K2[64][512] __half2 = 128 KiB (8 rows/wave,
//       wave-private: written and read only by the owning wave -> no barriers)
//   Cross-wave col reduce: 2-round tree in sm4[4][1024] (16 KiB):
//   waves 0-3 write partials, barrier, waves 4-7 accumulate, barrier.
// Col pass -> one atomicAdd per col per block -> 8-block arrival counter per
// (batch,iter) -> coherent readback (protocol unchanged from passing rounds).
// Plain launch (graph-capture safe); 1 block/CU at grid==CU-count makes
// deadlock unreachable; spin bounded as insurance.
// Global traffic: read g once (134 MB) + write out once (134 MB) + ~3 MB/iter.
#define BB 32
#define NN 1024
#define SHIFT 8.0f
#define GS_ITERS 20

__global__ __launch_bounds__(512) void sinkhorn_persist(
    const float* __restrict__ g, float* __restrict__ out,
    float* __restrict__ colsum, int* __restrict__ cnt)
{
    const int b    = blockIdx.x >> 3;     // batch
    const int blk  = blockIdx.x & 7;      // row-chunk within batch (128 rows)
    const int wave = threadIdx.x >> 6;    // 0..7
    const int lane = threadIdx.x & 63;
    const int tid  = threadIdx.x;         // 0..511
    const int rowR0 = blk * 128 + wave * 8;        // this wave's register rows
    const int rowL0 = blk * 128 + 64 + wave * 8;   // this wave's LDS rows
    const int lds0  = wave * 8;                    // local index of LDS rows

    const float* gb = g + ((size_t)b << 20);
    float* ob = out + ((size_t)b << 20);

    __shared__ __half2 K2[64][512];       // 128 KiB: chunk rows 64..127
    __shared__ float   sm4[4][1024];      // 16 KiB reduce/broadcast

    __half2 kr[8][8];                     // chunk rows 0..63 (8 per wave)
    float uR[8], uL[8];
    float vr[16];

    // ---- build: load g (float2), exp(g-SHIFT), pack fp16; fp32 row sums ----
    #pragma unroll
    for (int p = 0; p < 8; ++p) {         // register rows
        const float2* grow = (const float2*)(gb + (((size_t)(rowR0 + p)) << 10)) + lane;
        float s = 0.f;
        #pragma unroll
        for (int c = 0; c < 8; ++c) {
            float2 gg = grow[c * 64];     // cols c*128 + 2*lane, +1
            float e0 = __expf(gg.x - SHIFT);
            float e1 = __expf(gg.y - SHIFT);
            s += e0 + e1;
            kr[p][c] = __floats2half2_rn(e0, e1);
        }
        #pragma unroll
        for (int off = 32; off; off >>= 1) s += __shfl_xor(s, off);
        uR[p] = 1.0f / s;
    }
    #pragma unroll
    for (int p = 0; p < 8; ++p) {         // LDS rows (wave-private)
        const float2* grow = (const float2*)(gb + (((size_t)(rowL0 + p)) << 10)) + lane;
        float s = 0.f;
        #pragma unroll
        for (int c = 0; c < 8; ++c) {
            float2 gg = grow[c * 64];
            float e0 = __expf(gg.x - SHIFT);
            float e1 = __expf(gg.y - SHIFT);
            s += e0 + e1;
            K2[lds0 + p][c * 64 + lane] = __floats2half2_rn(e0, e1);
        }
        #pragma unroll
        for (int off = 32; off; off >>= 1) s += __shfl_xor(s, off);
        uL[p] = 1.0f / s;
    }

    #pragma unroll 1
    for (int it = 0; it < GS_ITERS; ++it) {
        // ---- col partials over this wave's 16 rows ----
        float cs[16];
        #pragma unroll
        for (int c = 0; c < 16; ++c) cs[c] = 0.f;
        #pragma unroll
        for (int p = 0; p < 8; ++p) {     // register rows
            const float up = uR[p];
            #pragma unroll
            for (int c = 0; c < 8; ++c) {
                float2 f = __half22float2(kr[p][c]);
                cs[2*c]   = fmaf(f.x, up, cs[2*c]);
                cs[2*c+1] = fmaf(f.y, up, cs[2*c+1]);
            }
        }
        #pragma unroll
        for (int p = 0; p < 8; ++p) {     // LDS rows
            const float up = uL[p];
            #pragma unroll
            for (int c = 0; c < 8; ++c) {
                float2 f = __half22float2(K2[lds0 + p][c * 64 + lane]);
                cs[2*c]   = fmaf(f.x, up, cs[2*c]);
                cs[2*c+1] = fmaf(f.y, up, cs[2*c+1]);
            }
        }
        // ---- 2-round cross-wave tree into sm4[4][1024] ----
        if (wave < 4) {
            #pragma unroll
            for (int c = 0; c < 8; ++c)
                ((float2*)&sm4[wave][0])[c * 64 + lane] = make_float2(cs[2*c], cs[2*c+1]);
        }
        __syncthreads();
        if (wave >= 4) {
            #pragma unroll
            for (int c = 0; c < 8; ++c) {
                float2* p2 = ((float2*)&sm4[wave - 4][0]) + c * 64 + lane;
                float2 t = *p2;
                t.x += cs[2*c]; t.y += cs[2*c+1];
                *p2 = t;
            }
        }
        __syncthreads();

        // each thread reduces 2 columns: tid and tid+512
        float bp0 = sm4[0][tid] + sm4[1][tid] + sm4[2][tid] + sm4[3][tid];
        float bp1 = sm4[0][tid + 512] + sm4[1][tid + 512]
                  + sm4[2][tid + 512] + sm4[3][tid + 512];
        float* csit = colsum + (((size_t)(b * GS_ITERS + it)) << 10);
        atomicAdd(csit + tid, bp0);       // device-scope atomics (coherent)
        atomicAdd(csit + tid + 512, bp1);
        __syncthreads();                  // barrier drains vmcnt: adds issued

        // ---- 8-block arrival sync for this (batch, iter) ----
        if (tid == 0) {
            int* c8 = cnt + b * GS_ITERS + it;
            __hip_atomic_fetch_add(c8, 1, __ATOMIC_ACQ_REL, __HIP_MEMORY_SCOPE_AGENT);
            int spins = 0;
            while (__hip_atomic_load(c8, __ATOMIC_ACQUIRE, __HIP_MEMORY_SCOPE_AGENT) < 8) {
                __builtin_amdgcn_s_sleep(8);
                if (++spins > (1 << 22)) break;   // ~1s insurance: never hang
            }
        }
        __syncthreads();

        // coherent readback (agent-scope bypasses stale L1), bcast via LDS
        float tot0 = __hip_atomic_load(csit + tid,       __ATOMIC_RELAXED, __HIP_MEMORY_SCOPE_AGENT);
        float tot1 = __hip_atomic_load(csit + tid + 512, __ATOMIC_RELAXED, __HIP_MEMORY_SCOPE_AGENT);
        sm4[0][tid]       = 1.0f / tot0;
        sm4[0][tid + 512] = 1.0f / tot1;
        __syncthreads();
        #pragma unroll
        for (int c = 0; c < 8; ++c) {
            float2 vv = ((const float2*)&sm4[0][0])[c * 64 + lane];
            vr[2*c] = vv.x; vr[2*c+1] = vv.y;
        }

        // ---- row pass -> new u (skip after last col pass) ----
        if (it < GS_ITERS - 1) {
            #pragma unroll
            for (int p = 0; p < 8; ++p) { // register rows
                float s = 0.f;
                #pragma unroll
                for (int c = 0; c < 8; ++c) {
                    float2 f = __half22float2(kr[p][c]);
                    s = fmaf(f.x, vr[2*c],   s);
                    s = fmaf(f.y, vr[2*c+1], s);
                }
                #pragma unroll
                for (int off = 32; off; off >>= 1) s += __shfl_xor(s, off);
                uR[p] = 1.0f / s;
            }
            #pragma unroll
            for (int p = 0; p < 8; ++p) { // LDS rows
                float s = 0.f;
                #pragma unroll
                for (int c = 0; c < 8; ++c) {
                    float2 f = __half22float2(K2[lds0 + p][c * 64 + lane]);
                    s = fmaf(f.x, vr[2*c],   s);
                    s = fmaf(f.y, vr[2*c+1], s);
                }
                #pragma unroll
                for (int off = 32; off; off >>= 1) s += __shfl_xor(s, off);
                uL[p] = 1.0f / s;
            }
        }
        __syncthreads();                  // protect sm4 before next iter writes
    }

    // ---- out = K .* (u v^T), coalesced float2 stores ----
    #pragma unroll
    for (int p = 0; p < 8; ++p) {         // register rows
        float2* orow = (float2*)(ob + (((size_t)(rowR0 + p)) << 10)) + lane;
        const float up = uR[p];
        #pragma unroll
        for (int c = 0; c < 8; ++c) {
            float2 f = __half22float2(kr[p][c]);
            orow[c * 64] = make_float2(f.x * up * vr[2*c], f.y * up * vr[2*c+1]);
        }
    }
    #pragma unroll
    for (int p = 0; p < 8; ++p) {         // LDS rows
        float2* orow = (float2*)(ob + (((size_t)(rowL0 + p)) << 10)) + lane;
        const float up = uL[p];
        #pragma unroll
        for (int c = 0; c < 8; ++c) {
            float2 f = __half22float2(K2[lds0 + p][c * 64 + lane]);
            orow[c * 64] = make_float2(f.x * up * vr[2*c], f.y * up * vr[2*c+1]);
        }
    }
}

// ---------- fallback path (tiny ws, log-domain, kernel-per-step) ----------

template<bool USE_V>
__global__ __launch_bounds__(256) void row_step(const float* __restrict__ g,
                                                const float* __restrict__ v,
                                                float* __restrict__ t) {
    const int wave = threadIdx.x >> 6, lane = threadIdx.x & 63;
    const int row = blockIdx.x * 4 + wave;
    const int b = row >> 10;
    const float4* grow = (const float4*)(g + ((size_t)row << 10));
    const float4* vrow = (const float4*)(v + ((size_t)b << 10));
    float x[16];
    #pragma unroll
    for (int k = 0; k < 4; k++) {
        float4 gg = grow[lane + 64 * k];
        if (USE_V) {
            float4 vv = vrow[lane + 64 * k];
            x[4*k+0] = gg.x + vv.x; x[4*k+1] = gg.y + vv.y;
            x[4*k+2] = gg.z + vv.z; x[4*k+3] = gg.w + vv.w;
        } else {
            x[4*k+0] = gg.x; x[4*k+1] = gg.y; x[4*k+2] = gg.z; x[4*k+3] = gg.w;
        }
    }
    float m = -INFINITY;
    #pragma unroll
    for (int k = 0; k < 16; k++) m = fmaxf(m, x[k]);
    #pragma unroll
    for (int off = 32; off; off >>= 1) m = fmaxf(m, __shfl_xor(m, off));
    float s = 0.f;
    #pragma unroll
    for (int k = 0; k < 16; k++) s += __expf(x[k] - m);
    #pragma unroll
    for (int off = 32; off; off >>= 1) s += __shfl_xor(s, off);
    if (lane == 0) t[row] = -(m + __logf(s));
}

__global__ __launch_bounds__(256) void col_step(const float* __restrict__ g,
                                                const float* __restrict__ t,
                                                float* __restrict__ v) {
    const int b = blockIdx.x >> 4, tile = blockIdx.x & 15;
    const int tx = threadIdx.x & 63, ty = threadIdx.x >> 6;
    const int j = tile * 64 + tx;
    const float* gp = g + ((size_t)b << 20) + j;
    const float* tp = t + (b << 10);
    float m = -INFINITY, s = 0.f;
    for (int it = 0; it < 256; it += 8) {
        float xv[8];
        #pragma unroll
        for (int u2 = 0; u2 < 8; u2++) {
            int i = ((it + u2) << 2) + ty;
            xv[u2] = gp[(size_t)i << 10] + tp[i];
        }
        #pragma unroll
        for (int u2 = 0; u2 < 8; u2++) {
            float nm = fmaxf(m, xv[u2]);
            s = s * __expf(m - nm) + __expf(xv[u2] - nm);
            m = nm;
        }
    }
    __shared__ float sm[4][64];
    __shared__ float ss[4][64];
    sm[ty][tx] = m; ss[ty][tx] = s;
    __syncthreads();
    if (ty == 0) {
        float M = sm[0][tx], S = ss[0][tx];
        #pragma unroll
        for (int k = 1; k < 4; k++) {
            float mk = sm[k][tx], sk = ss[k][tx];
            float nm = fmaxf(M, mk);
            S = S * __expf(M - nm) + sk * __expf(mk - nm);
            M = nm;
        }
        v[(b << 10) + j] = -(M + __logf(S));
    }
}

__global__ __launch_bounds__(256) void finalize_k(const float* __restrict__ g,
                                                  const float* __restrict__ t,
                                                  const float* __restrict__ v,
                                                  float* __restrict__ out) {
    const size_t idx4 = (size_t)blockIdx.x * 256 + threadIdx.x;
    const size_t base = idx4 << 2;
    const int row = (int)(base >> 10), b = row >> 10;
    const int j = (int)(base & 1023);
    const float ti = t[row];
    float4 gg = ((const float4*)g)[idx4];
    float4 vv = ((const float4*)(v + ((size_t)b << 10)))[j >> 2];
    float4 o;
    o.x = __expf(gg.x + ti + vv.x);
    o.y = __expf(gg.y + ti + vv.y);
    o.z = __expf(gg.z + ti + vv.z);
    o.w = __expf(gg.w + ti + vv.w);
    ((float4*)out)[idx4] = o;
}

extern "C" void kernel_launch(void* const* d_in, const int* in_sizes, int n_in,
                              void* d_out, int out_size, void* d_ws, size_t ws_size,
                              hipStream_t stream) {
    const float* g = (const float*)d_in[3];   // gumbel noise; inputs 0..2 dead
    float* out = (float*)d_out;
    const size_t needCS  = (size_t)BB * GS_ITERS * NN * sizeof(float);  // 2.62 MB
    const size_t needCnt = (size_t)BB * GS_ITERS * sizeof(int);         // 2.5 KB

    if (ws_size >= needCS + needCnt) {
        float* colsum = (float*)d_ws;
        int* cnt = (int*)((char*)d_ws + needCS);
        hipMemsetAsync(d_ws, 0, needCS + needCnt, stream);
        sinkhorn_persist<<<BB * 8, 512, 0, stream>>>(g, out, colsum, cnt);
    } else {
        float* t = (float*)d_ws;
        float* v = t + BB * NN;
        row_step<false><<<8192, 256, 0, stream>>>(g, nullptr, t);
        col_step<<<512, 256, 0, stream>>>(g, t, v);
        for (int it = 1; it < 20; it++) {
            row_step<true><<<8192, 256, 0, stream>>>(g, v, t);
            col_step<<<512, 256, 0, stream>>>(g, t, v);
        }
        finalize_k<<<32768, 256, 0, stream>>>(g, t, v, out);
    }
}

// Round 6
// 630.284 us; speedup vs baseline: 2.4494x; 1.2545x over previous
//
#include <hip/hip_runtime.h>
#include <hip/hip_fp16.h>
#include <math.h>

// B=32, N=1024 Sinkhorn (20 iters). scores@W+b cancels under the first row-lse
// -> inputs 0..2 dead. Linear domain: K = exp(g - 8) (fp16, scale-invariant),
// u_i = 1/(K v)_i, v_j = 1/(K^T u)_j, out = K .* (u v^T).
//
// ROUND-2..4: backend pins this kernel at a 128-VGPR budget; kr[16][8] spilled
// (FETCH 1.6GB). ROUND-5: 64 rows reg + 64 rows LDS -> FETCH 0.60GB, 630us,
// but VGPR demand (~140: kr64+u16+vr16+cs16+temps) still exceeded 128 -> ~15
// regs spilled, ~440MB residual scratch traffic. THIS ROUND: cut demand to
// ~105 so 128 suffices BY CONSTRUCTION:
//   - vr[16] eliminated: 1/colsum lives in LDS vbc[1024], read by row pass/fin
//   - cs[16] -> cs[8]: columns processed in two 512-wide halves; cross-wave
//     reduce in smr[8][512] per half (h-loop fully unrolled -> kr static idx)
// Geometry/sync unchanged from the passing rounds:
//   grid = 256 blocks (8 per batch) x 512 threads (8 waves), 1 block/CU.
//   rows [0,64) in kr[8][8] __half2 (8/wave); rows [64,128) in K2[64][512]
//   LDS (8/wave, wave-private). LDS total 151552 B.
// Col pass -> LDS reduce -> one atomicAdd per col per block -> 8-block arrival
// counter per (batch,iter) -> coherent readback. Plain launch (graph-capture
// safe); 1 block/CU at grid==CU-count makes deadlock unreachable; bounded spin.
// Global traffic: read g once (134 MB) + write out once (134 MB) + ~3 MB/iter.
#define BB 32
#define NN 1024
#define SHIFT 8.0f
#define GS_ITERS 20

__global__ __launch_bounds__(512) void sinkhorn_persist(
    const float* __restrict__ g, float* __restrict__ out,
    float* __restrict__ colsum, int* __restrict__ cnt)
{
    const int b    = blockIdx.x >> 3;     // batch
    const int blk  = blockIdx.x & 7;      // row-chunk within batch (128 rows)
    const int wave = threadIdx.x >> 6;    // 0..7
    const int lane = threadIdx.x & 63;
    const int tid  = threadIdx.x;         // 0..511
    const int rowR0 = blk * 128 + wave * 8;        // this wave's register rows
    const int rowL0 = blk * 128 + 64 + wave * 8;   // this wave's LDS rows
    const int lds0  = wave * 8;                    // local index of LDS rows

    const float* gb = g + ((size_t)b << 20);
    float* ob = out + ((size_t)b << 20);

    __shared__ __half2 K2[64][512];       // 128 KiB: chunk rows 64..127
    __shared__ float   smr[8][512];       // 16 KiB: cross-wave reduce (half)
    __shared__ float   vbc[1024];         // 4 KiB: 1/colsum broadcast

    __half2 kr[8][8];                     // chunk rows 0..63 (8 per wave)
    float uR[8], uL[8];

    // ---- build: load g (float2), exp(g-SHIFT), pack fp16; fp32 row sums ----
    #pragma unroll 2
    for (int p = 0; p < 8; ++p) {         // register rows
        const float2* grow = (const float2*)(gb + (((size_t)(rowR0 + p)) << 10)) + lane;
        float s = 0.f;
        #pragma unroll
        for (int c = 0; c < 8; ++c) {
            float2 gg = grow[c * 64];     // cols c*128 + 2*lane, +1
            float e0 = __expf(gg.x - SHIFT);
            float e1 = __expf(gg.y - SHIFT);
            s += e0 + e1;
            kr[p][c] = __floats2half2_rn(e0, e1);
        }
        #pragma unroll
        for (int off = 32; off; off >>= 1) s += __shfl_xor(s, off);
        uR[p] = 1.0f / s;
    }
    #pragma unroll 2
    for (int p = 0; p < 8; ++p) {         // LDS rows (wave-private)
        const float2* grow = (const float2*)(gb + (((size_t)(rowL0 + p)) << 10)) + lane;
        float s = 0.f;
        #pragma unroll
        for (int c = 0; c < 8; ++c) {
            float2 gg = grow[c * 64];
            float e0 = __expf(gg.x - SHIFT);
            float e1 = __expf(gg.y - SHIFT);
            s += e0 + e1;
            K2[lds0 + p][c * 64 + lane] = __floats2half2_rn(e0, e1);
        }
        #pragma unroll
        for (int off = 32; off; off >>= 1) s += __shfl_xor(s, off);
        uL[p] = 1.0f / s;
    }

    #pragma unroll 1
    for (int it = 0; it < GS_ITERS; ++it) {
        float* csit = colsum + (((size_t)(b * GS_ITERS + it)) << 10);

        // ---- col pass in two 512-column halves (cs[8] live, not cs[16]) ----
        #pragma unroll
        for (int h = 0; h < 2; ++h) {
            float cs[8];
            #pragma unroll
            for (int c = 0; c < 8; ++c) cs[c] = 0.f;
            #pragma unroll
            for (int p = 0; p < 8; ++p) {     // register rows
                const float up = uR[p];
                #pragma unroll
                for (int c = 0; c < 4; ++c) {
                    float2 f = __half22float2(kr[p][h * 4 + c]);
                    cs[2*c]   = fmaf(f.x, up, cs[2*c]);
                    cs[2*c+1] = fmaf(f.y, up, cs[2*c+1]);
                }
            }
            #pragma unroll
            for (int p = 0; p < 8; ++p) {     // LDS rows
                const float up = uL[p];
                #pragma unroll
                for (int c = 0; c < 4; ++c) {
                    float2 f = __half22float2(K2[lds0 + p][(h * 4 + c) * 64 + lane]);
                    cs[2*c]   = fmaf(f.x, up, cs[2*c]);
                    cs[2*c+1] = fmaf(f.y, up, cs[2*c+1]);
                }
            }
            // all 8 waves write their partials for this half
            #pragma unroll
            for (int c = 0; c < 4; ++c)
                ((float2*)&smr[wave][0])[c * 64 + lane] = make_float2(cs[2*c], cs[2*c+1]);
            __syncthreads();
            // each thread reduces one column of this half, one atomic per col
            float bp = 0.f;
            #pragma unroll
            for (int w = 0; w < 8; ++w) bp += smr[w][tid];
            atomicAdd(csit + h * 512 + tid, bp);   // device-scope (coherent)
            __syncthreads();                       // smr reusable; vmcnt drained
        }

        // ---- 8-block arrival sync for this (batch, iter) ----
        if (tid == 0) {
            int* c8 = cnt + b * GS_ITERS + it;
            __hip_atomic_fetch_add(c8, 1, __ATOMIC_ACQ_REL, __HIP_MEMORY_SCOPE_AGENT);
            int spins = 0;
            while (__hip_atomic_load(c8, __ATOMIC_ACQUIRE, __HIP_MEMORY_SCOPE_AGENT) < 8) {
                __builtin_amdgcn_s_sleep(8);
                if (++spins > (1 << 22)) break;   // ~1s insurance: never hang
            }
        }
        __syncthreads();

        // coherent readback -> 1/colsum broadcast in LDS (vbc), no vr regs
        float tot0 = __hip_atomic_load(csit + tid,       __ATOMIC_RELAXED, __HIP_MEMORY_SCOPE_AGENT);
        float tot1 = __hip_atomic_load(csit + tid + 512, __ATOMIC_RELAXED, __HIP_MEMORY_SCOPE_AGENT);
        vbc[tid]       = 1.0f / tot0;
        vbc[tid + 512] = 1.0f / tot1;
        __syncthreads();

        // ---- row pass -> new u (skip after last col pass) ----
        if (it < GS_ITERS - 1) {
            const float2* v2 = (const float2*)vbc;
            #pragma unroll
            for (int p = 0; p < 8; ++p) { // register rows
                float s = 0.f;
                #pragma unroll
                for (int c = 0; c < 8; ++c) {
                    float2 f = __half22float2(kr[p][c]);
                    float2 vv = v2[c * 64 + lane];
                    s = fmaf(f.x, vv.x, s);
                    s = fmaf(f.y, vv.y, s);
                }
                #pragma unroll
                for (int off = 32; off; off >>= 1) s += __shfl_xor(s, off);
                uR[p] = 1.0f / s;
            }
            #pragma unroll
            for (int p = 0; p < 8; ++p) { // LDS rows
                float s = 0.f;
                #pragma unroll
                for (int c = 0; c < 8; ++c) {
                    float2 f = __half22float2(K2[lds0 + p][c * 64 + lane]);
                    float2 vv = v2[c * 64 + lane];
                    s = fmaf(f.x, vv.x, s);
                    s = fmaf(f.y, vv.y, s);
                }
                #pragma unroll
                for (int off = 32; off; off >>= 1) s += __shfl_xor(s, off);
                uL[p] = 1.0f / s;
            }
        }
        // no trailing barrier needed: next iter's smr writes are >=2 barriers
        // away from this iter's last smr read; vbc reads precede next readback
    }

    // ---- out = K .* (u v^T), coalesced float2 stores (v from vbc) ----
    {
        const float2* v2 = (const float2*)vbc;
        #pragma unroll
        for (int p = 0; p < 8; ++p) {     // register rows
            float2* orow = (float2*)(ob + (((size_t)(rowR0 + p)) << 10)) + lane;
            const float up = uR[p];
            #pragma unroll
            for (int c = 0; c < 8; ++c) {
                float2 f = __half22float2(kr[p][c]);
                float2 vv = v2[c * 64 + lane];
                orow[c * 64] = make_float2(f.x * up * vv.x, f.y * up * vv.y);
            }
        }
        #pragma unroll
        for (int p = 0; p < 8; ++p) {     // LDS rows
            float2* orow = (float2*)(ob + (((size_t)(rowL0 + p)) << 10)) + lane;
            const float up = uL[p];
            #pragma unroll
            for (int c = 0; c < 8; ++c) {
                float2 f = __half22float2(K2[lds0 + p][c * 64 + lane]);
                float2 vv = v2[c * 64 + lane];
                orow[c * 64] = make_float2(f.x * up * vv.x, f.y * up * vv.y);
            }
        }
    }
}

// ---------- fallback path (tiny ws, log-domain, kernel-per-step) ----------

template<bool USE_V>
__global__ __launch_bounds__(256) void row_step(const float* __restrict__ g,
                                                const float* __restrict__ v,
                                                float* __restrict__ t) {
    const int wave = threadIdx.x >> 6, lane = threadIdx.x & 63;
    const int row = blockIdx.x * 4 + wave;
    const int b = row >> 10;
    const float4* grow = (const float4*)(g + ((size_t)row << 10));
    const float4* vrow = (const float4*)(v + ((size_t)b << 10));
    float x[16];
    #pragma unroll
    for (int k = 0; k < 4; k++) {
        float4 gg = grow[lane + 64 * k];
        if (USE_V) {
            float4 vv = vrow[lane + 64 * k];
            x[4*k+0] = gg.x + vv.x; x[4*k+1] = gg.y + vv.y;
            x[4*k+2] = gg.z + vv.z; x[4*k+3] = gg.w + vv.w;
        } else {
            x[4*k+0] = gg.x; x[4*k+1] = gg.y; x[4*k+2] = gg.z; x[4*k+3] = gg.w;
        }
    }
    float m = -INFINITY;
    #pragma unroll
    for (int k = 0; k < 16; k++) m = fmaxf(m, x[k]);
    #pragma unroll
    for (int off = 32; off; off >>= 1) m = fmaxf(m, __shfl_xor(m, off));
    float s = 0.f;
    #pragma unroll
    for (int k = 0; k < 16; k++) s += __expf(x[k] - m);
    #pragma unroll
    for (int off = 32; off; off >>= 1) s += __shfl_xor(s, off);
    if (lane == 0) t[row] = -(m + __logf(s));
}

__global__ __launch_bounds__(256) void col_step(const float* __restrict__ g,
                                                const float* __restrict__ t,
                                                float* __restrict__ v) {
    const int b = blockIdx.x >> 4, tile = blockIdx.x & 15;
    const int tx = threadIdx.x & 63, ty = threadIdx.x >> 6;
    const int j = tile * 64 + tx;
    const float* gp = g + ((size_t)b << 20) + j;
    const float* tp = t + (b << 10);
    float m = -INFINITY, s = 0.f;
    for (int it = 0; it < 256; it += 8) {
        float xv[8];
        #pragma unroll
        for (int u2 = 0; u2 < 8; u2++) {
            int i = ((it + u2) << 2) + ty;
            xv[u2] = gp[(size_t)i << 10] + tp[i];
        }
        #pragma unroll
        for (int u2 = 0; u2 < 8; u2++) {
            float nm = fmaxf(m, xv[u2]);
            s = s * __expf(m - nm) + __expf(xv[u2] - nm);
            m = nm;
        }
    }
    __shared__ float sm[4][64];
    __shared__ float ss[4][64];
    sm[ty][tx] = m; ss[ty][tx] = s;
    __syncthreads();
    if (ty == 0) {
        float M = sm[0][tx], S = ss[0][tx];
        #pragma unroll
        for (int k = 1; k < 4; k++) {
            float mk = sm[k][tx], sk = ss[k][tx];
            float nm = fmaxf(M, mk);
            S = S * __expf(M - nm) + sk * __expf(mk - nm);
            M = nm;
        }
        v[(b << 10) + j] = -(M + __logf(S));
    }
}

__global__ __launch_bounds__(256) void finalize_k(const float* __restrict__ g,
                                                  const float* __restrict__ t,
                                                  const float* __restrict__ v,
                                                  float* __restrict__ out) {
    const size_t idx4 = (size_t)blockIdx.x * 256 + threadIdx.x;
    const size_t base = idx4 << 2;
    const int row = (int)(base >> 10), b = row >> 10;
    const int j = (int)(base & 1023);
    const float ti = t[row];
    float4 gg = ((const float4*)g)[idx4];
    float4 vv = ((const float4*)(v + ((size_t)b << 10)))[j >> 2];
    float4 o;
    o.x = __expf(gg.x + ti + vv.x);
    o.y = __expf(gg.y + ti + vv.y);
    o.z = __expf(gg.z + ti + vv.z);
    o.w = __expf(gg.w + ti + vv.w);
    ((float4*)out)[idx4] = o;
}

extern "C" void kernel_launch(void* const* d_in, const int* in_sizes, int n_in,
                              void* d_out, int out_size, void* d_ws, size_t ws_size,
                              hipStream_t stream) {
    const float* g = (const float*)d_in[3];   // gumbel noise; inputs 0..2 dead
    float* out = (float*)d_out;
    const size_t needCS  = (size_t)BB * GS_ITERS * NN * sizeof(float);  // 2.62 MB
    const size_t needCnt = (size_t)BB * GS_ITERS * sizeof(int);         // 2.5 KB

    if (ws_size >= needCS + needCnt) {
        float* colsum = (float*)d_ws;
        int* cnt = (int*)((char*)d_ws + needCS);
        hipMemsetAsync(d_ws, 0, needCS + needCnt, stream);
        sinkhorn_persist<<<BB * 8, 512, 0, stream>>>(g, out, colsum, cnt);
    } else {
        float* t = (float*)d_ws;
        float* v = t + BB * NN;
        row_step<false><<<8192, 256, 0, stream>>>(g, nullptr, t);
        col_step<<<512, 256, 0, stream>>>(g, t, v);
        for (int it = 1; it < 20; it++) {
            row_step<true><<<8192, 256, 0, stream>>>(g, v, t);
            col_step<<<512, 256, 0, stream>>>(g, t, v);
        }
        finalize_k<<<32768, 256, 0, stream>>>(g, t, v, out);
    }
}